// Round 14
// baseline (173.456 us; speedup 1.0000x reference)
//
#include <hip/hip_runtime.h>
#include <math.h>

#define NN 4096
#define DD 256
#define DFF 512
#define HH 8
#define DHH 64
#define CAP_C 256
#define CAP_B 1024

// ws layout (float-element offsets)
#define OFF_KB     0         /* bf16 K [4096][512] */
#define OFF_VB     1048576
#define OFF_QB     2097152
#define OFF_LOCALB 5242880   /* bf16 local [4096][256] */
#define OFF_STC    5767168   /* fp32 64*8*4096 [a][b] (direct store) */
#define OFF_STBP   7864320   /* fp32 4 partials x 8*8*4096 (direct store) */
#define OFF_BSUM   8912896   /* fp32 8*1024 — zeroed in prep */
#define OFF_CNT    8921088   /* 256 ints   — zeroed in prep */
#define OFF_WQKVT  8921344   /* bf16 Wqkv^T [1536][256] */
#define OFF_WOUTT  9117952   /* bf16 Wout^T [256][1024] */
#define OFF_LISTS  9249024   /* 49152 ints */
#define OFF_LPART  9298176   /* fp32 [256][8][256] = 524288 */

typedef __attribute__((ext_vector_type(8))) short bf16x8;
typedef __attribute__((ext_vector_type(4))) float floatx4;

__device__ __forceinline__ float gelu_f(float x) {
    const float c = 0.7978845608028654f;
    float t = tanhf(c * (x + 0.044715f * x * x * x));
    return 0.5f * x * (1.0f + t);
}

__device__ __forceinline__ unsigned short f2b(float f) {
    union { float f; unsigned int u; } v; v.f = f;
    unsigned int r = (v.u + 0x7FFFu + ((v.u >> 16) & 1u)) >> 16;
    return (unsigned short)r;
}

// ---------------------------------------------------------------------------
// prep, flat grid 1473:
//  [0,640)      weight transpose-cast
//  [640,896)    Lpart partial batch sums, 16 rows/block
//  [896,1408)   cast local -> bf16
//  [1408,1472)  zero out (4 MB, einsum accumulates into it atomically)
//  [1472]       zero Bsum + cnt
// ---------------------------------------------------------------------------
__global__ __launch_bounds__(256) void prep_kernel(
    const float* __restrict__ local,
    const float* __restrict__ Wk, const float* __restrict__ Wv,
    const float* __restrict__ Wq, const float* __restrict__ Wout,
    const int* __restrict__ batch, const int* __restrict__ mask,
    unsigned short* __restrict__ Wqkvt, unsigned short* __restrict__ Woutt,
    unsigned short* __restrict__ localb,
    float* __restrict__ Lpart, float* __restrict__ out,
    float* __restrict__ zero_base)
{
    const int bid = blockIdx.x, tid = threadIdx.x;
    if (bid < 640) {
        const float* src; unsigned short* dst; int R, C, r0, c0;
        if (bid < 384) {
            int m = bid >> 7, ti = bid & 127;
            src = (m == 0) ? Wk : (m == 1) ? Wv : Wq;
            dst = Wqkvt + (size_t)m * 512 * 256;
            R = 256; C = 512;
            r0 = (ti >> 4) * 32; c0 = (ti & 15) * 32;
        } else {
            int ti = bid - 384;
            src = Wout; dst = Woutt;
            R = 1024; C = 256;
            r0 = (ti >> 3) * 32; c0 = (ti & 7) * 32;
        }
        __shared__ float Tl[32][33];
        int ty = tid >> 3, tx = tid & 7;
        float4 v = *(const float4*)(src + (size_t)(r0 + ty) * C + c0 + tx * 4);
        Tl[tx * 4 + 0][ty] = v.x;
        Tl[tx * 4 + 1][ty] = v.y;
        Tl[tx * 4 + 2][ty] = v.z;
        Tl[tx * 4 + 3][ty] = v.w;
        __syncthreads();
        ushort4 o;
        o.x = f2b(Tl[ty][tx * 4 + 0]);
        o.y = f2b(Tl[ty][tx * 4 + 1]);
        o.z = f2b(Tl[ty][tx * 4 + 2]);
        o.w = f2b(Tl[ty][tx * 4 + 3]);
        *(ushort4*)(dst + (size_t)(c0 + ty) * R + r0 + tx * 4) = o;
    } else if (bid < 896) {
        int p = bid - 640;
        float accl[8] = {};
        int n0 = p * 16;
#pragma unroll
        for (int r = 0; r < 16; ++r) {
            int n = n0 + r;
            float v = local[(size_t)n * DD + tid];
            int bb = batch[n];
            float vm = mask[n] ? v : 0.0f;
#pragma unroll
            for (int b = 0; b < 8; ++b)
                accl[b] += (bb == b) ? vm : 0.0f;
        }
#pragma unroll
        for (int b = 0; b < 8; ++b)
            Lpart[(size_t)p * 2048 + b * 256 + tid] = accl[b];
    } else if (bid < 1408) {
        int p = bid - 896;
        size_t base = (size_t)p * 2048 + tid * 8;
        float4 a0 = *(const float4*)(local + base);
        float4 a1 = *(const float4*)(local + base + 4);
        ushort4 p0, p1;
        p0.x = f2b(a0.x); p0.y = f2b(a0.y); p0.z = f2b(a0.z); p0.w = f2b(a0.w);
        p1.x = f2b(a1.x); p1.y = f2b(a1.y); p1.z = f2b(a1.z); p1.w = f2b(a1.w);
        *(ushort4*)(localb + base) = p0;
        *(ushort4*)(localb + base + 4) = p1;
    } else if (bid < 1472) {
        int p = bid - 1408;
        float4 z4 = make_float4(0.f, 0.f, 0.f, 0.f);
        float4* o4 = (float4*)out;
#pragma unroll
        for (int i = 0; i < 16; ++i)
            o4[p * 4096 + i * 256 + tid] = z4;
    } else {
        float4 z4 = make_float4(0.f, 0.f, 0.f, 0.f);
        for (int i = tid; i < 2112; i += 256)   // 8448 floats (Bsum + cnt)
            ((float4*)zero_base)[i] = z4;
    }
}

// ---------------------------------------------------------------------------
// qkv dispatch, flat grid 1552:
//  u < 1536: 64x64 MFMA GEMM tiles
//  [1536,1552): segment list build (LDS-aggregated atomics)
// ---------------------------------------------------------------------------
__global__ __launch_bounds__(256) void qkv_kernel(
    const unsigned short* __restrict__ localb,
    const unsigned short* __restrict__ Wqkvt,
    const float* __restrict__ bk, const float* __restrict__ bv,
    const float* __restrict__ bq, unsigned short* __restrict__ KVQb,
    const int* __restrict__ chain, const int* __restrict__ batch,
    const int* __restrict__ mask, int* __restrict__ cnt,
    int* __restrict__ lists)
{
    __shared__ __align__(16) char smem[18944];
    const int u = blockIdx.x, tid = threadIdx.x;
    int* cntc_m   = cnt;
    int* cntc_all = cnt + 64;
    int* cntb_m   = cnt + 128;
    int* cntb_all = cnt + 136;
    int* listc_m   = lists;
    int* listc_all = listc_m + 64 * CAP_C;
    int* listb_m   = listc_all + 64 * CAP_C;
    int* listb_all = listb_m + 8 * CAP_B;

    if (u < 1536) {
        typedef unsigned short (*t72)[72];
        t72 Asl = (t72)smem;
        t72 Bsl = (t72)(smem + 9216);
        const int wave = tid >> 6, lane = tid & 63;
        const int q = lane >> 4, r = lane & 15;
        const int cx = u % 24, ry = u / 24;
        const int row0 = ry * 64, cg0 = cx * 64;

        floatx4 acc[4] = {};
        for (int kk = 0; kk < 256; kk += 64) {
#pragma unroll
            for (int i = 0; i < 2; ++i) {
                int lin = tid * 2 + i;
                int rr = lin >> 3, kc = (lin & 7) * 8;
                *(float4*)&Asl[rr][kc] =
                    *(const float4*)(localb + (size_t)(row0 + rr) * DD + kk + kc);
                *(float4*)&Bsl[rr][kc] =
                    *(const float4*)(Wqkvt + (size_t)(cg0 + rr) * DD + kk + kc);
            }
            __syncthreads();
#pragma unroll
            for (int sub = 0; sub < 2; ++sub) {
                bf16x8 a = *(const bf16x8*)&Asl[wave * 16 + r][sub * 32 + q * 8];
#pragma unroll
                for (int c = 0; c < 4; ++c) {
                    bf16x8 b = *(const bf16x8*)&Bsl[c * 16 + r][sub * 32 + q * 8];
                    acc[c] = __builtin_amdgcn_mfma_f32_16x16x32_bf16(a, b, acc[c], 0, 0, 0);
                }
            }
            __syncthreads();
        }
        const int sel = cg0 >> 9;
        const int do_gelu = (sel != 1);
        const float* bias = (sel == 0) ? bk : (sel == 1) ? bv : bq;
        unsigned short* C = KVQb + (size_t)sel * (NN * DFF);
#pragma unroll
        for (int c = 0; c < 4; ++c) {
            int colw = (cg0 + c * 16 + r) & 511;
            float bb = bias[colw];
#pragma unroll
            for (int i = 0; i < 4; ++i) {
                int row = row0 + wave * 16 + q * 4 + i;
                float o = acc[c][i] + bb;
                if (do_gelu) o = gelu_f(o);
                C[(size_t)row * DFF + colw] = f2b(o);
            }
        }
    } else {
        int* sh = (int*)smem;
        int* hc_m = sh;        int* hc_all = sh + 64;
        int* hb_m = sh + 128;  int* hb_all = sh + 136;
        int* pc_m = sh + 144;  int* pc_all = sh + 208;
        int* pb_m = sh + 272;  int* pb_all = sh + 280;
        if (tid < 64) { hc_m[tid] = 0; hc_all[tid] = 0; }
        if (tid < 8)  { hb_m[tid] = 0; hb_all[tid] = 0; }
        __syncthreads();
        int n = (u - 1536) * 256 + tid;
        int c = chain[n], b = batch[n], m = mask[n];
        int rc_all = atomicAdd(&hc_all[c], 1);
        int rb_all = atomicAdd(&hb_all[b], 1);
        int rc_m = -1, rb_m = -1;
        if (m) { rc_m = atomicAdd(&hc_m[c], 1); rb_m = atomicAdd(&hb_m[b], 1); }
        __syncthreads();
        if (tid < 64) {
            pc_all[tid] = atomicAdd(&cntc_all[tid], hc_all[tid]);
            pc_m[tid]   = atomicAdd(&cntc_m[tid],   hc_m[tid]);
        }
        if (tid < 8) {
            pb_all[tid] = atomicAdd(&cntb_all[tid], hb_all[tid]);
            pb_m[tid]   = atomicAdd(&cntb_m[tid],   hb_m[tid]);
        }
        __syncthreads();
        int ia = pc_all[c] + rc_all; if (ia < CAP_C) listc_all[c * CAP_C + ia] = n;
        int ib = pb_all[b] + rb_all; if (ib < CAP_B) listb_all[b * CAP_B + ib] = n;
        if (m) {
            int ja = pc_m[c] + rc_m; if (ja < CAP_C) listc_m[c * CAP_C + ja] = n;
            int jb = pb_m[b] + rb_m; if (jb < CAP_B) listb_m[b * CAP_B + jb] = n;
        }
    }
}

// ---------------------------------------------------------------------------
// mid: seg-outer MFMA + bsum rider, flat grid 832, ALL direct store:
//  u < 256: batch (z=u>>6, seg=(u>>3)&7, h=u&7), z-split 4 -> STbp[z]
//  [256,768): chain (t=u-256: seg=t>>3, h=t&7) -> STc
//  [768,832): bsum (reduce 256 Lpart partials, Lk @ Wbias slice -> Bsum)
// ---------------------------------------------------------------------------
__global__ __launch_bounds__(256) void mid_kernel(
    const unsigned short* __restrict__ Kb, const unsigned short* __restrict__ Vb,
    const int* __restrict__ cnt, const int* __restrict__ lists,
    float* __restrict__ STc, float* __restrict__ STbp,
    const float* __restrict__ Lpart, const float* __restrict__ Wbias,
    float* __restrict__ Bsum)
{
    const int u = blockIdx.x, tid = threadIdx.x;
    __shared__ unsigned short Ktl[64][36];
    __shared__ unsigned short Vtl[64][36];

    if (u >= 768) {
        int t = u - 768;                 // 0..63
        const int seg = t >> 3, kz = t & 7;
        float (*part)[32] = (float(*)[32])Ktl;
        float* Lk = ((float*)Ktl) + 256;
        {
            int k = tid & 31, pg = tid >> 5;
            float s = 0.0f;
#pragma unroll 8
            for (int p = pg * 32; p < pg * 32 + 32; ++p)
                s += Lpart[(size_t)p * 2048 + seg * 256 + kz * 32 + k];
            part[pg][k] = s;
        }
        __syncthreads();
        if (tid < 32) {
            float s = 0.0f;
#pragma unroll
            for (int pg = 0; pg < 8; ++pg) s += part[pg][tid];
            Lk[tid] = s;
        }
        __syncthreads();
        float4 a4 = make_float4(0, 0, 0, 0);
        for (int k = 0; k < 32; ++k) {
            float l = Lk[k];
            float4 w = *(const float4*)(Wbias + (size_t)(kz * 32 + k) * 1024 + tid * 4);
            a4.x += l * w.x; a4.y += l * w.y; a4.z += l * w.z; a4.w += l * w.w;
        }
        float* o = Bsum + (size_t)seg * 1024 + tid * 4;
        atomicAdd(o + 0, a4.x); atomicAdd(o + 1, a4.y);
        atomicAdd(o + 2, a4.z); atomicAdd(o + 3, a4.w);
        return;
    }

    const int* cntc_m = cnt;
    const int* cntb_m = cnt + 128;
    const int* listc_m = lists;
    const int* listb_m = lists + 2 * 64 * CAP_C;

    int seg, h, r0, r1, cap;
    const int* list; float* ST;
    if (u < 256) {
        int z = u >> 6; seg = (u >> 3) & 7; h = u & 7;
        cap = CAP_B; list = listb_m;
        int c = min(cntb_m[seg], CAP_B);
        int chunk = (c + 3) / 4;
        r0 = z * chunk; r1 = min(c, r0 + chunk);
        ST = STbp + (size_t)z * 262144 + ((size_t)(seg * HH + h) << 12);
    } else {
        int t = u - 256;
        seg = t >> 3; h = t & 7;
        cap = CAP_C; list = listc_m;
        r0 = 0; r1 = min(cntc_m[seg], CAP_C);
        ST = STc + ((size_t)(seg * HH + h) << 12);
    }

    const int wave = tid >> 6, lane = tid & 63;
    const int la = lane & 15, kq = lane >> 4;

    floatx4 acc4[4] = {};
    for (int g = r0; g < r1; g += 32) {
#pragma unroll
        for (int it = 0; it < 2; ++it) {
            int item = tid + it * 256;
            int nl = item & 31, aq = item >> 5;
            int gg = g + nl;
            ushort4 kz4 = make_ushort4(0, 0, 0, 0);
            ushort4 vz4 = make_ushort4(0, 0, 0, 0);
            if (gg < r1) {
                int nn = list[seg * cap + gg];
                kz4 = *(const ushort4*)(Kb + (size_t)nn * DFF + h * DHH + aq * 4);
                vz4 = *(const ushort4*)(Vb + (size_t)nn * DFF + h * DHH + aq * 4);
            }
            Ktl[aq * 4 + 0][nl] = kz4.x; Ktl[aq * 4 + 1][nl] = kz4.y;
            Ktl[aq * 4 + 2][nl] = kz4.z; Ktl[aq * 4 + 3][nl] = kz4.w;
            Vtl[aq * 4 + 0][nl] = vz4.x; Vtl[aq * 4 + 1][nl] = vz4.y;
            Vtl[aq * 4 + 2][nl] = vz4.z; Vtl[aq * 4 + 3][nl] = vz4.w;
        }
        __syncthreads();
        bf16x8 a = *(const bf16x8*)&Ktl[wave * 16 + la][kq * 8];
#pragma unroll
        for (int bt = 0; bt < 4; ++bt) {
            bf16x8 b = *(const bf16x8*)&Vtl[bt * 16 + la][kq * 8];
            acc4[bt] = __builtin_amdgcn_mfma_f32_16x16x32_bf16(a, b, acc4[bt], 0, 0, 0);
        }
        __syncthreads();
    }

#pragma unroll
    for (int bt = 0; bt < 4; ++bt)
#pragma unroll
        for (int rg = 0; rg < 4; ++rg) {
            int aa = wave * 16 + kq * 4 + rg;
            int bb2 = bt * 16 + la;
            ST[aa * 64 + bb2] = acc4[bt][rg];
        }
}

// ---------------------------------------------------------------------------
// einsum FUSED with final GEMM, flat grid 1024:
//  id<512 chain (colbase h*128), else batch (colbase h*128+64, z=8).
// Per g-group of 64 rows:
//   P = q @ S^T (+bias) -> Qsl bf16 (own rows per wave)
//   out[n,:] += P_rows @ Wout[colbase:colbase+64,:]   (fp32 atomicAdd)
// Wout slice staged once per block as Wsl[oc][k] bf16. No attnb buffer.
// ---------------------------------------------------------------------------
__global__ __launch_bounds__(256) void einsum_fused_kernel(
    const float* __restrict__ STc, const float* __restrict__ STbp,
    const int* __restrict__ cnt, const int* __restrict__ lists,
    const unsigned short* __restrict__ Qb, const int* __restrict__ batch,
    const float* __restrict__ Bsum, const float* __restrict__ b_bias,
    const unsigned short* __restrict__ Woutt, float* __restrict__ out)
{
    const int id = blockIdx.x, tid = threadIdx.x;
    const int* cntc_m   = cnt;
    const int* cntc_all = cnt + 64;
    const int* cntb_m   = cnt + 128;
    const int* cntb_all = cnt + 136;
    const int* listc_all = lists + 64 * CAP_C;
    const int* listb_all = lists + 2 * 64 * CAP_C + 8 * CAP_B;

    int seg, h, outoff, cap, r0, r1;
    const int* list;
    float scaleS;
    bool is_chain;
    if (id < 512) {
        seg = id >> 3; h = id & 7; outoff = 0;
        list = listc_all; cap = CAP_C; is_chain = true;
        scaleS = 1.0f / fmaxf((float)min(cntc_m[seg], CAP_C), 1e-6f);
        r0 = 0; r1 = min(cntc_all[seg], CAP_C);
    } else {
        int t = id - 512;
        seg = t >> 6; h = (t >> 3) & 7;
        int z = t & 7;
        outoff = 64;
        list = listb_all; cap = CAP_B; is_chain = false;
        scaleS = 1.0f / fmaxf((float)min(cntb_m[seg], CAP_B), 1e-6f);
        int c = min(cntb_all[seg], CAP_B);
        int chunk = (c + 7) / 8;
        r0 = z * chunk; r1 = min(c, r0 + chunk);
    }

    __shared__ unsigned short Sbl[64][72];
    __shared__ unsigned short Qsl[64][72];
    __shared__ unsigned short Wsl[256][72];
    __shared__ float Bf[8][64];
    __shared__ int nrow[64];
    __shared__ int nbb[64];

    const int wave = tid >> 6, lane = tid & 63;
    const int la = lane & 15, kq = lane >> 4;
    const int colbase = h * 128 + outoff;
    const int wrow = wave * 16;

    // stage S (scaled bf16)
#pragma unroll
    for (int i = 0; i < 4; ++i) {
        int e = tid + i * 256;
        float4 v;
        if (is_chain) {
            v = *(const float4*)(STc + ((size_t)(seg * HH + h) << 12) + (size_t)e * 4);
        } else {
            const float* Sg = STbp + ((size_t)(seg * HH + h) << 12) + (size_t)e * 4;
            float4 v0 = *(const float4*)(Sg);
            float4 v1 = *(const float4*)(Sg + 262144);
            float4 v2 = *(const float4*)(Sg + 524288);
            float4 v3 = *(const float4*)(Sg + 786432);
            v.x = v0.x + v1.x + v2.x + v3.x;
            v.y = v0.y + v1.y + v2.y + v3.y;
            v.z = v0.z + v1.z + v2.z + v3.z;
            v.w = v0.w + v1.w + v2.w + v3.w;
        }
        int a = e >> 4, b = (e & 15) * 4;
        ushort4 o;
        o.x = f2b(v.x * scaleS); o.y = f2b(v.y * scaleS);
        o.z = f2b(v.z * scaleS); o.w = f2b(v.w * scaleS);
        *(ushort4*)&Sbl[a][b] = o;
    }
    // stage Wout slice: Wsl[oc][j] = Woutt[oc][colbase+j], oc<256, j<64
#pragma unroll
    for (int i = 0; i < 8; ++i) {
        int e = tid + i * 256;
        int oc = e >> 3, j8 = (e & 7) * 8;
        *(float4*)&Wsl[oc][j8] =
            *(const float4*)(Woutt + (size_t)oc * 1024 + colbase + j8);
    }
    // bias table
#pragma unroll
    for (int e = tid; e < 512; e += 256) {
        int bbq = e >> 6, j = e & 63;
        float cm = (float)min(cntb_m[bbq], CAP_B);
        float inv = 1.0f / fmaxf(cm, 1e-6f);
        int col = colbase + j;
        Bf[bbq][j] = (Bsum[(size_t)bbq * 1024 + col] + cm * b_bias[col]) * inv;
    }
    __syncthreads();

    for (int g = r0; g < r1; g += 64) {
        if (tid < 64) {
            int gg = g + tid;
            int n = (gg < r1) ? list[seg * cap + gg] : -1;
            nrow[tid] = n;
            nbb[tid] = (n >= 0) ? batch[n] : 0;
        }
        __syncthreads();
        {
            int row = tid & 63, pr = tid >> 6;
            int n = nrow[row];
            if (n >= 0) {
#pragma unroll
                for (int it = 0; it < 2; ++it) {
                    int off = (pr + it * 4) * 8;
                    *(float4*)&Qsl[row][off] =
                        *(const float4*)(Qb + (size_t)n * DFF + h * DHH + off);
                }
            }
        }
        __syncthreads();

        // matmul 1: P = q @ S^T
        floatx4 acc[4] = {};
#pragma unroll
        for (int ks = 0; ks < 2; ++ks) {
            bf16x8 a = *(const bf16x8*)&Qsl[wrow + la][ks * 32 + kq * 8];
#pragma unroll
            for (int ct = 0; ct < 4; ++ct) {
                bf16x8 b = *(const bf16x8*)&Sbl[ct * 16 + la][ks * 32 + kq * 8];
                acc[ct] = __builtin_amdgcn_mfma_f32_16x16x32_bf16(a, b, acc[ct], 0, 0, 0);
            }
        }
        // P + bias -> Qsl bf16 (each wave writes only its own 16 rows)
#pragma unroll
        for (int ct = 0; ct < 4; ++ct)
#pragma unroll
            for (int rg = 0; rg < 4; ++rg) {
                int rowl = wrow + kq * 4 + rg;
                float bias = Bf[nbb[rowl]][ct * 16 + la];
                Qsl[rowl][ct * 16 + la] = f2b(acc[ct][rg] + bias);
            }

        // matmul 2: out[rows, 0:256] += P_rows @ WoutSlice (own rows per wave)
        floatx4 acc2[16] = {};
#pragma unroll
        for (int ks = 0; ks < 2; ++ks) {
            bf16x8 a = *(const bf16x8*)&Qsl[wrow + la][ks * 32 + kq * 8];
#pragma unroll
            for (int ct = 0; ct < 16; ++ct) {
                bf16x8 b = *(const bf16x8*)&Wsl[ct * 16 + la][ks * 32 + kq * 8];
                acc2[ct] = __builtin_amdgcn_mfma_f32_16x16x32_bf16(a, b, acc2[ct], 0, 0, 0);
            }
        }
#pragma unroll
        for (int ct = 0; ct < 16; ++ct)
#pragma unroll
            for (int rg = 0; rg < 4; ++rg) {
                int rowl = wrow + kq * 4 + rg;
                int n = nrow[rowl];
                if (n >= 0)
                    atomicAdd(&out[(size_t)n * DD + ct * 16 + la], acc2[ct][rg]);
            }
        __syncthreads();
    }
}

extern "C" void kernel_launch(void* const* d_in, const int* in_sizes, int n_in,
                              void* d_out, int out_size, void* d_ws, size_t ws_size,
                              hipStream_t stream)
{
    const float* local   = (const float*)d_in[0];
    const int*   chain   = (const int*)d_in[1];
    const int*   batch   = (const int*)d_in[2];
    const int*   mask    = (const int*)d_in[3];
    const float* W_key   = (const float*)d_in[4];
    const float* b_key   = (const float*)d_in[5];
    const float* W_value = (const float*)d_in[6];
    const float* b_value = (const float*)d_in[7];
    const float* W_query = (const float*)d_in[8];
    const float* b_query = (const float*)d_in[9];
    const float* W_bias  = (const float*)d_in[10];
    const float* b_bias  = (const float*)d_in[11];
    const float* W_out   = (const float*)d_in[12];
    float* out = (float*)d_out;

    float* ws = (float*)d_ws;
    unsigned short* Kb     = (unsigned short*)(ws + OFF_KB);
    unsigned short* Qb     = (unsigned short*)(ws + OFF_QB);
    unsigned short* localb = (unsigned short*)(ws + OFF_LOCALB);
    float* STc    = ws + OFF_STC;
    float* STbp   = ws + OFF_STBP;
    float* Bsum   = ws + OFF_BSUM;
    int*   cnt    = (int*)(ws + OFF_CNT);
    unsigned short* Wqkvt = (unsigned short*)(ws + OFF_WQKVT);
    unsigned short* Woutt = (unsigned short*)(ws + OFF_WOUTT);
    int*   lists  = (int*)(ws + OFF_LISTS);
    float* Lpart  = ws + OFF_LPART;

    dim3 blk(256);

    prep_kernel<<<dim3(1473), blk, 0, stream>>>(
        local, W_key, W_value, W_query, W_out, batch, mask,
        Wqkvt, Woutt, localb, Lpart, out, ws + OFF_BSUM);

    qkv_kernel<<<dim3(1552), blk, 0, stream>>>(
        localb, Wqkvt, b_key, b_value, b_query, Kb,
        chain, batch, mask, cnt, lists);

    mid_kernel<<<dim3(832), blk, 0, stream>>>(
        Kb, (const unsigned short*)(ws + OFF_VB), cnt, lists, STc, STbp,
        Lpart, W_bias, Bsum);

    einsum_fused_kernel<<<dim3(1024), blk, 0, stream>>>(
        STc, STbp, cnt, lists, Qb, batch, Bsum, b_bias, Woutt, out);
}

// Round 15
// 132.613 us; speedup vs baseline: 1.3080x; 1.3080x over previous
//
#include <hip/hip_runtime.h>
#include <math.h>

#define NN 4096
#define DD 256
#define DFF 512
#define HH 8
#define DHH 64
#define CAP_C 256
#define CAP_B 1024

// ws layout (float-element offsets)
#define OFF_KB     0         /* bf16 K [4096][512] */
#define OFF_VB     1048576
#define OFF_QB     2097152
#define OFF_ATTNB  3145728   /* bf16 attn [4096][1024] */
#define OFF_LOCALB 5242880   /* bf16 local [4096][256] */
#define OFF_STC    5767168   /* fp32 64*8*4096 [a][b] (direct store) */
#define OFF_STBP   7864320   /* fp32 4 partials x 8*8*4096 (direct store) */
#define OFF_BSUM   8912896   /* fp32 8*1024 — zeroed in prep */
#define OFF_CNT    8921088   /* 256 ints   — zeroed in prep */
#define OFF_WQKVT  8921344   /* bf16 Wqkv^T [1536][256] */
#define OFF_WOUTT  9117952   /* bf16 Wout^T [256][1024] */
#define OFF_LISTS  9249024   /* 49152 ints */
#define OFF_LPART  9298176   /* fp32 [256][8][256] = 524288 */

typedef __attribute__((ext_vector_type(8))) short bf16x8;
typedef __attribute__((ext_vector_type(4))) float floatx4;

__device__ __forceinline__ float gelu_f(float x) {
    const float c = 0.7978845608028654f;
    float t = tanhf(c * (x + 0.044715f * x * x * x));
    return 0.5f * x * (1.0f + t);
}

__device__ __forceinline__ unsigned short f2b(float f) {
    union { float f; unsigned int u; } v; v.f = f;
    unsigned int r = (v.u + 0x7FFFu + ((v.u >> 16) & 1u)) >> 16;
    return (unsigned short)r;
}

// ---------------------------------------------------------------------------
// prep, flat grid 1409 (round-11 proven):
//  [0,640)     weight transpose-cast
//  [640,896)   Lpart partial batch sums, 16 rows/block
//  [896,1408)  cast local -> bf16
//  [1408]      zero Bsum + cnt
// ---------------------------------------------------------------------------
__global__ __launch_bounds__(256) void prep_kernel(
    const float* __restrict__ local,
    const float* __restrict__ Wk, const float* __restrict__ Wv,
    const float* __restrict__ Wq, const float* __restrict__ Wout,
    const int* __restrict__ batch, const int* __restrict__ mask,
    unsigned short* __restrict__ Wqkvt, unsigned short* __restrict__ Woutt,
    unsigned short* __restrict__ localb,
    float* __restrict__ Lpart, float* __restrict__ zero_base)
{
    const int bid = blockIdx.x, tid = threadIdx.x;
    if (bid < 640) {
        const float* src; unsigned short* dst; int R, C, r0, c0;
        if (bid < 384) {
            int m = bid >> 7, ti = bid & 127;
            src = (m == 0) ? Wk : (m == 1) ? Wv : Wq;
            dst = Wqkvt + (size_t)m * 512 * 256;
            R = 256; C = 512;
            r0 = (ti >> 4) * 32; c0 = (ti & 15) * 32;
        } else {
            int ti = bid - 384;
            src = Wout; dst = Woutt;
            R = 1024; C = 256;
            r0 = (ti >> 3) * 32; c0 = (ti & 7) * 32;
        }
        __shared__ float Tl[32][33];
        int ty = tid >> 3, tx = tid & 7;
        float4 v = *(const float4*)(src + (size_t)(r0 + ty) * C + c0 + tx * 4);
        Tl[tx * 4 + 0][ty] = v.x;
        Tl[tx * 4 + 1][ty] = v.y;
        Tl[tx * 4 + 2][ty] = v.z;
        Tl[tx * 4 + 3][ty] = v.w;
        __syncthreads();
        ushort4 o;
        o.x = f2b(Tl[ty][tx * 4 + 0]);
        o.y = f2b(Tl[ty][tx * 4 + 1]);
        o.z = f2b(Tl[ty][tx * 4 + 2]);
        o.w = f2b(Tl[ty][tx * 4 + 3]);
        *(ushort4*)(dst + (size_t)(c0 + ty) * R + r0 + tx * 4) = o;
    } else if (bid < 896) {
        int p = bid - 640;
        float accl[8] = {};
        int n0 = p * 16;
#pragma unroll
        for (int r = 0; r < 16; ++r) {
            int n = n0 + r;
            float v = local[(size_t)n * DD + tid];
            int bb = batch[n];
            float vm = mask[n] ? v : 0.0f;
#pragma unroll
            for (int b = 0; b < 8; ++b)
                accl[b] += (bb == b) ? vm : 0.0f;
        }
#pragma unroll
        for (int b = 0; b < 8; ++b)
            Lpart[(size_t)p * 2048 + b * 256 + tid] = accl[b];
    } else if (bid < 1408) {
        int p = bid - 896;
        size_t base = (size_t)p * 2048 + tid * 8;
        float4 a0 = *(const float4*)(local + base);
        float4 a1 = *(const float4*)(local + base + 4);
        ushort4 p0, p1;
        p0.x = f2b(a0.x); p0.y = f2b(a0.y); p0.z = f2b(a0.z); p0.w = f2b(a0.w);
        p1.x = f2b(a1.x); p1.y = f2b(a1.y); p1.z = f2b(a1.z); p1.w = f2b(a1.w);
        *(ushort4*)(localb + base) = p0;
        *(ushort4*)(localb + base + 4) = p1;
    } else {
        float4 z4 = make_float4(0.f, 0.f, 0.f, 0.f);
        for (int i = tid; i < 2112; i += 256)   // 8448 floats (Bsum + cnt)
            ((float4*)zero_base)[i] = z4;
    }
}

// ---------------------------------------------------------------------------
// qkv dispatch, flat grid 1552 (bsum moved to mid):
//  u < 1536: 64x64 MFMA GEMM tiles
//  [1536,1552): segment list build (LDS-aggregated atomics)
// ---------------------------------------------------------------------------
__global__ __launch_bounds__(256) void qkv_kernel(
    const unsigned short* __restrict__ localb,
    const unsigned short* __restrict__ Wqkvt,
    const float* __restrict__ bk, const float* __restrict__ bv,
    const float* __restrict__ bq, unsigned short* __restrict__ KVQb,
    const int* __restrict__ chain, const int* __restrict__ batch,
    const int* __restrict__ mask, int* __restrict__ cnt,
    int* __restrict__ lists)
{
    __shared__ __align__(16) char smem[18944];
    const int u = blockIdx.x, tid = threadIdx.x;
    int* cntc_m   = cnt;
    int* cntc_all = cnt + 64;
    int* cntb_m   = cnt + 128;
    int* cntb_all = cnt + 136;
    int* listc_m   = lists;
    int* listc_all = listc_m + 64 * CAP_C;
    int* listb_m   = listc_all + 64 * CAP_C;
    int* listb_all = listb_m + 8 * CAP_B;

    if (u < 1536) {
        typedef unsigned short (*t72)[72];
        t72 Asl = (t72)smem;
        t72 Bsl = (t72)(smem + 9216);
        const int wave = tid >> 6, lane = tid & 63;
        const int q = lane >> 4, r = lane & 15;
        const int cx = u % 24, ry = u / 24;
        const int row0 = ry * 64, cg0 = cx * 64;

        floatx4 acc[4] = {};
        for (int kk = 0; kk < 256; kk += 64) {
#pragma unroll
            for (int i = 0; i < 2; ++i) {
                int lin = tid * 2 + i;
                int rr = lin >> 3, kc = (lin & 7) * 8;
                *(float4*)&Asl[rr][kc] =
                    *(const float4*)(localb + (size_t)(row0 + rr) * DD + kk + kc);
                *(float4*)&Bsl[rr][kc] =
                    *(const float4*)(Wqkvt + (size_t)(cg0 + rr) * DD + kk + kc);
            }
            __syncthreads();
#pragma unroll
            for (int sub = 0; sub < 2; ++sub) {
                bf16x8 a = *(const bf16x8*)&Asl[wave * 16 + r][sub * 32 + q * 8];
#pragma unroll
                for (int c = 0; c < 4; ++c) {
                    bf16x8 b = *(const bf16x8*)&Bsl[c * 16 + r][sub * 32 + q * 8];
                    acc[c] = __builtin_amdgcn_mfma_f32_16x16x32_bf16(a, b, acc[c], 0, 0, 0);
                }
            }
            __syncthreads();
        }
        const int sel = cg0 >> 9;
        const int do_gelu = (sel != 1);
        const float* bias = (sel == 0) ? bk : (sel == 1) ? bv : bq;
        unsigned short* C = KVQb + (size_t)sel * (NN * DFF);
#pragma unroll
        for (int c = 0; c < 4; ++c) {
            int colw = (cg0 + c * 16 + r) & 511;
            float bb = bias[colw];
#pragma unroll
            for (int i = 0; i < 4; ++i) {
                int row = row0 + wave * 16 + q * 4 + i;
                float o = acc[c][i] + bb;
                if (do_gelu) o = gelu_f(o);
                C[(size_t)row * DFF + colw] = f2b(o);
            }
        }
    } else {
        int* sh = (int*)smem;
        int* hc_m = sh;        int* hc_all = sh + 64;
        int* hb_m = sh + 128;  int* hb_all = sh + 136;
        int* pc_m = sh + 144;  int* pc_all = sh + 208;
        int* pb_m = sh + 272;  int* pb_all = sh + 280;
        if (tid < 64) { hc_m[tid] = 0; hc_all[tid] = 0; }
        if (tid < 8)  { hb_m[tid] = 0; hb_all[tid] = 0; }
        __syncthreads();
        int n = (u - 1536) * 256 + tid;
        int c = chain[n], b = batch[n], m = mask[n];
        int rc_all = atomicAdd(&hc_all[c], 1);
        int rb_all = atomicAdd(&hb_all[b], 1);
        int rc_m = -1, rb_m = -1;
        if (m) { rc_m = atomicAdd(&hc_m[c], 1); rb_m = atomicAdd(&hb_m[b], 1); }
        __syncthreads();
        if (tid < 64) {
            pc_all[tid] = atomicAdd(&cntc_all[tid], hc_all[tid]);
            pc_m[tid]   = atomicAdd(&cntc_m[tid],   hc_m[tid]);
        }
        if (tid < 8) {
            pb_all[tid] = atomicAdd(&cntb_all[tid], hb_all[tid]);
            pb_m[tid]   = atomicAdd(&cntb_m[tid],   hb_m[tid]);
        }
        __syncthreads();
        int ia = pc_all[c] + rc_all; if (ia < CAP_C) listc_all[c * CAP_C + ia] = n;
        int ib = pb_all[b] + rb_all; if (ib < CAP_B) listb_all[b * CAP_B + ib] = n;
        if (m) {
            int ja = pc_m[c] + rc_m; if (ja < CAP_C) listc_m[c * CAP_C + ja] = n;
            int jb = pb_m[b] + rb_m; if (jb < CAP_B) listb_m[b * CAP_B + jb] = n;
        }
    }
}

// ---------------------------------------------------------------------------
// mid: seg-outer MFMA + bsum rider, flat grid 832, ALL direct store:
//  u < 256: batch (z=u>>6, seg=(u>>3)&7, h=u&7), z-split 4 -> STbp[z]
//  [256,768): chain (t=u-256: seg=t>>3, h=t&7) -> STc
//  [768,832): bsum (reduce 256 Lpart partials, Lk @ Wbias slice -> Bsum)
// ---------------------------------------------------------------------------
__global__ __launch_bounds__(256) void mid_kernel(
    const unsigned short* __restrict__ Kb, const unsigned short* __restrict__ Vb,
    const int* __restrict__ cnt, const int* __restrict__ lists,
    float* __restrict__ STc, float* __restrict__ STbp,
    const float* __restrict__ Lpart, const float* __restrict__ Wbias,
    float* __restrict__ Bsum)
{
    const int u = blockIdx.x, tid = threadIdx.x;
    __shared__ unsigned short Ktl[64][36];
    __shared__ unsigned short Vtl[64][36];

    if (u >= 768) {
        int t = u - 768;                 // 0..63
        const int seg = t >> 3, kz = t & 7;
        float (*part)[32] = (float(*)[32])Ktl;    // 1 KB reuse
        float* Lk = ((float*)Ktl) + 256;          // 32 floats
        {
            int k = tid & 31, pg = tid >> 5;
            float s = 0.0f;
#pragma unroll 8
            for (int p = pg * 32; p < pg * 32 + 32; ++p)
                s += Lpart[(size_t)p * 2048 + seg * 256 + kz * 32 + k];
            part[pg][k] = s;
        }
        __syncthreads();
        if (tid < 32) {
            float s = 0.0f;
#pragma unroll
            for (int pg = 0; pg < 8; ++pg) s += part[pg][tid];
            Lk[tid] = s;
        }
        __syncthreads();
        float4 a4 = make_float4(0, 0, 0, 0);
        for (int k = 0; k < 32; ++k) {
            float l = Lk[k];
            float4 w = *(const float4*)(Wbias + (size_t)(kz * 32 + k) * 1024 + tid * 4);
            a4.x += l * w.x; a4.y += l * w.y; a4.z += l * w.z; a4.w += l * w.w;
        }
        float* o = Bsum + (size_t)seg * 1024 + tid * 4;
        atomicAdd(o + 0, a4.x); atomicAdd(o + 1, a4.y);
        atomicAdd(o + 2, a4.z); atomicAdd(o + 3, a4.w);
        return;
    }

    const int* cntc_m = cnt;
    const int* cntb_m = cnt + 128;
    const int* listc_m = lists;
    const int* listb_m = lists + 2 * 64 * CAP_C;

    int seg, h, r0, r1, cap;
    const int* list; float* ST;
    if (u < 256) {
        int z = u >> 6; seg = (u >> 3) & 7; h = u & 7;
        cap = CAP_B; list = listb_m;
        int c = min(cntb_m[seg], CAP_B);
        int chunk = (c + 3) / 4;
        r0 = z * chunk; r1 = min(c, r0 + chunk);
        ST = STbp + (size_t)z * 262144 + ((size_t)(seg * HH + h) << 12);
    } else {
        int t = u - 256;
        seg = t >> 3; h = t & 7;
        cap = CAP_C; list = listc_m;
        r0 = 0; r1 = min(cntc_m[seg], CAP_C);
        ST = STc + ((size_t)(seg * HH + h) << 12);
    }

    const int wave = tid >> 6, lane = tid & 63;
    const int la = lane & 15, kq = lane >> 4;

    floatx4 acc4[4] = {};
    for (int g = r0; g < r1; g += 32) {
#pragma unroll
        for (int it = 0; it < 2; ++it) {
            int item = tid + it * 256;
            int nl = item & 31, aq = item >> 5;
            int gg = g + nl;
            ushort4 kz4 = make_ushort4(0, 0, 0, 0);
            ushort4 vz4 = make_ushort4(0, 0, 0, 0);
            if (gg < r1) {
                int nn = list[seg * cap + gg];
                kz4 = *(const ushort4*)(Kb + (size_t)nn * DFF + h * DHH + aq * 4);
                vz4 = *(const ushort4*)(Vb + (size_t)nn * DFF + h * DHH + aq * 4);
            }
            Ktl[aq * 4 + 0][nl] = kz4.x; Ktl[aq * 4 + 1][nl] = kz4.y;
            Ktl[aq * 4 + 2][nl] = kz4.z; Ktl[aq * 4 + 3][nl] = kz4.w;
            Vtl[aq * 4 + 0][nl] = vz4.x; Vtl[aq * 4 + 1][nl] = vz4.y;
            Vtl[aq * 4 + 2][nl] = vz4.z; Vtl[aq * 4 + 3][nl] = vz4.w;
        }
        __syncthreads();
        bf16x8 a = *(const bf16x8*)&Ktl[wave * 16 + la][kq * 8];
#pragma unroll
        for (int bt = 0; bt < 4; ++bt) {
            bf16x8 b = *(const bf16x8*)&Vtl[bt * 16 + la][kq * 8];
            acc4[bt] = __builtin_amdgcn_mfma_f32_16x16x32_bf16(a, b, acc4[bt], 0, 0, 0);
        }
        __syncthreads();
    }

#pragma unroll
    for (int bt = 0; bt < 4; ++bt)
#pragma unroll
        for (int rg = 0; rg < 4; ++rg) {
            int aa = wave * 16 + kq * 4 + rg;
            int bb2 = bt * 16 + la;
            ST[aa * 64 + bb2] = acc4[bt][rg];
        }
}

// ---------------------------------------------------------------------------
// einsum (MFMA), flat grid 1024: id<512 chain (outoff 0, S from STc), else
// batch (outoff 64, z=8, S = sum of 4 STbp partials).
// ---------------------------------------------------------------------------
__global__ __launch_bounds__(256) void einsum_kernel(
    const float* __restrict__ STc, const float* __restrict__ STbp,
    const int* __restrict__ cnt, const int* __restrict__ lists,
    const unsigned short* __restrict__ Qb, const int* __restrict__ batch,
    const float* __restrict__ Bsum, const float* __restrict__ b_bias,
    unsigned short* __restrict__ attnb)
{
    const int id = blockIdx.x, tid = threadIdx.x;
    const int* cntc_m   = cnt;
    const int* cntc_all = cnt + 64;
    const int* cntb_m   = cnt + 128;
    const int* cntb_all = cnt + 136;
    const int* listc_all = lists + 64 * CAP_C;
    const int* listb_all = lists + 2 * 64 * CAP_C + 8 * CAP_B;

    int seg, h, outoff, cap, r0, r1;
    const int* list;
    float scaleS;
    bool is_chain;
    if (id < 512) {
        seg = id >> 3; h = id & 7; outoff = 0;
        list = listc_all; cap = CAP_C; is_chain = true;
        scaleS = 1.0f / fmaxf((float)min(cntc_m[seg], CAP_C), 1e-6f);
        r0 = 0; r1 = min(cntc_all[seg], CAP_C);
    } else {
        int t = id - 512;
        seg = t >> 6; h = (t >> 3) & 7;
        int z = t & 7;
        outoff = 64;
        list = listb_all; cap = CAP_B; is_chain = false;
        scaleS = 1.0f / fmaxf((float)min(cntb_m[seg], CAP_B), 1e-6f);
        int c = min(cntb_all[seg], CAP_B);
        int chunk = (c + 7) / 8;
        r0 = z * chunk; r1 = min(c, r0 + chunk);
    }

    __shared__ unsigned short Sbl[64][72];
    __shared__ unsigned short Qsl[64][72];
    __shared__ float Bf[8][64];
    __shared__ int nrow[64];
    __shared__ int nbb[64];

    const int wave = tid >> 6, lane = tid & 63;
    const int la = lane & 15, kq = lane >> 4;
    const int colbase = h * 128 + outoff;

#pragma unroll
    for (int i = 0; i < 4; ++i) {
        int e = tid + i * 256;
        float4 v;
        if (is_chain) {
            v = *(const float4*)(STc + ((size_t)(seg * HH + h) << 12) + (size_t)e * 4);
        } else {
            const float* Sg = STbp + ((size_t)(seg * HH + h) << 12) + (size_t)e * 4;
            float4 v0 = *(const float4*)(Sg);
            float4 v1 = *(const float4*)(Sg + 262144);
            float4 v2 = *(const float4*)(Sg + 524288);
            float4 v3 = *(const float4*)(Sg + 786432);
            v.x = v0.x + v1.x + v2.x + v3.x;
            v.y = v0.y + v1.y + v2.y + v3.y;
            v.z = v0.z + v1.z + v2.z + v3.z;
            v.w = v0.w + v1.w + v2.w + v3.w;
        }
        int a = e >> 4, b = (e & 15) * 4;
        ushort4 o;
        o.x = f2b(v.x * scaleS); o.y = f2b(v.y * scaleS);
        o.z = f2b(v.z * scaleS); o.w = f2b(v.w * scaleS);
        *(ushort4*)&Sbl[a][b] = o;
    }
#pragma unroll
    for (int e = tid; e < 512; e += 256) {
        int bbq = e >> 6, j = e & 63;
        float cm = (float)min(cntb_m[bbq], CAP_B);
        float inv = 1.0f / fmaxf(cm, 1e-6f);
        int col = colbase + j;
        Bf[bbq][j] = (Bsum[(size_t)bbq * 1024 + col] + cm * b_bias[col]) * inv;
    }
    __syncthreads();

    for (int g = r0; g < r1; g += 64) {
        if (tid < 64) {
            int gg = g + tid;
            int n = (gg < r1) ? list[seg * cap + gg] : -1;
            nrow[tid] = n;
            nbb[tid] = (n >= 0) ? batch[n] : 0;
        }
        __syncthreads();
        {
            int row = tid & 63, pr = tid >> 6;
            int n = nrow[row];
            if (n >= 0) {
#pragma unroll
                for (int it = 0; it < 2; ++it) {
                    int off = (pr + it * 4) * 8;
                    *(float4*)&Qsl[row][off] =
                        *(const float4*)(Qb + (size_t)n * DFF + h * DHH + off);
                }
            }
        }
        __syncthreads();

        floatx4 acc[4] = {};
#pragma unroll
        for (int ks = 0; ks < 2; ++ks) {
            bf16x8 a = *(const bf16x8*)&Qsl[wave * 16 + la][ks * 32 + kq * 8];
#pragma unroll
            for (int ct = 0; ct < 4; ++ct) {
                bf16x8 b = *(const bf16x8*)&Sbl[ct * 16 + la][ks * 32 + kq * 8];
                acc[ct] = __builtin_amdgcn_mfma_f32_16x16x32_bf16(a, b, acc[ct], 0, 0, 0);
            }
        }
#pragma unroll
        for (int ct = 0; ct < 4; ++ct)
#pragma unroll
            for (int rg = 0; rg < 4; ++rg) {
                int rowl = wave * 16 + kq * 4 + rg;
                float bias = Bf[nbb[rowl]][ct * 16 + la];
                Qsl[rowl][ct * 16 + la] = f2b(acc[ct][rg] + bias);
            }
        __syncthreads();
        {
            int row = tid & 63, pr = tid >> 6;
            int n = nrow[row];
            if (n >= 0) {
#pragma unroll
                for (int it = 0; it < 2; ++it) {
                    int off = (pr + it * 4) * 8;
                    *(float4*)(attnb + (size_t)n * 1024 + colbase + off) =
                        *(const float4*)&Qsl[row][off];
                }
            }
        }
        __syncthreads();
    }
}

// ---------------------------------------------------------------------------
// Final GEMM: out = attnb @ W_out. 32x32 tile, BK=128 (8 iters), grid (8,128).
// ---------------------------------------------------------------------------
__global__ __launch_bounds__(256) void mfma_gemm_final(
    const unsigned short* __restrict__ A, const unsigned short* __restrict__ Bt,
    float* __restrict__ out)
{
    const int K = 1024;
    __shared__ unsigned short Asl[32][136];
    __shared__ unsigned short Bsl[32][136];
    const int tid = threadIdx.x;
    const int wave = tid >> 6, lane = tid & 63;
    const int q = lane >> 4, r = lane & 15;
    const int row0 = blockIdx.y * 32, cg0 = blockIdx.x * 32;
    const int wrow = (wave & 1) * 16, wcol = (wave >> 1) * 16;

    floatx4 acc = {};
    for (int kk = 0; kk < K; kk += 128) {
#pragma unroll
        for (int t = 0; t < 2; ++t) {
            int idx = tid + t * 256;
            int rr = idx >> 4, kc = (idx & 15) * 8;
            *(float4*)&Asl[rr][kc] = *(const float4*)(A + (size_t)(row0 + rr) * K + kk + kc);
            *(float4*)&Bsl[rr][kc] = *(const float4*)(Bt + (size_t)(cg0 + rr) * K + kk + kc);
        }
        __syncthreads();
#pragma unroll
        for (int sub = 0; sub < 4; ++sub) {
            bf16x8 a = *(const bf16x8*)&Asl[wrow + r][sub * 32 + q * 8];
            bf16x8 b = *(const bf16x8*)&Bsl[wcol + r][sub * 32 + q * 8];
            acc = __builtin_amdgcn_mfma_f32_16x16x32_bf16(a, b, acc, 0, 0, 0);
        }
        __syncthreads();
    }
    int col = cg0 + wcol + r;
#pragma unroll
    for (int i = 0; i < 4; ++i) {
        int row = row0 + wrow + q * 4 + i;
        out[(size_t)row * DD + col] = acc[i];
    }
}

extern "C" void kernel_launch(void* const* d_in, const int* in_sizes, int n_in,
                              void* d_out, int out_size, void* d_ws, size_t ws_size,
                              hipStream_t stream)
{
    const float* local   = (const float*)d_in[0];
    const int*   chain   = (const int*)d_in[1];
    const int*   batch   = (const int*)d_in[2];
    const int*   mask    = (const int*)d_in[3];
    const float* W_key   = (const float*)d_in[4];
    const float* b_key   = (const float*)d_in[5];
    const float* W_value = (const float*)d_in[6];
    const float* b_value = (const float*)d_in[7];
    const float* W_query = (const float*)d_in[8];
    const float* b_query = (const float*)d_in[9];
    const float* W_bias  = (const float*)d_in[10];
    const float* b_bias  = (const float*)d_in[11];
    const float* W_out   = (const float*)d_in[12];
    float* out = (float*)d_out;

    float* ws = (float*)d_ws;
    unsigned short* Kb     = (unsigned short*)(ws + OFF_KB);
    unsigned short* Qb     = (unsigned short*)(ws + OFF_QB);
    unsigned short* attnb  = (unsigned short*)(ws + OFF_ATTNB);
    unsigned short* localb = (unsigned short*)(ws + OFF_LOCALB);
    float* STc    = ws + OFF_STC;
    float* STbp   = ws + OFF_STBP;
    float* Bsum   = ws + OFF_BSUM;
    int*   cnt    = (int*)(ws + OFF_CNT);
    unsigned short* Wqkvt = (unsigned short*)(ws + OFF_WQKVT);
    unsigned short* Woutt = (unsigned short*)(ws + OFF_WOUTT);
    int*   lists  = (int*)(ws + OFF_LISTS);
    float* Lpart  = ws + OFF_LPART;

    dim3 blk(256);

    prep_kernel<<<dim3(1409), blk, 0, stream>>>(
        local, W_key, W_value, W_query, W_out, batch, mask,
        Wqkvt, Woutt, localb, Lpart, ws + OFF_BSUM);

    qkv_kernel<<<dim3(1552), blk, 0, stream>>>(
        localb, Wqkvt, b_key, b_value, b_query, Kb,
        chain, batch, mask, cnt, lists);

    mid_kernel<<<dim3(832), blk, 0, stream>>>(
        Kb, (const unsigned short*)(ws + OFF_VB), cnt, lists, STc, STbp,
        Lpart, W_bias, Bsum);

    einsum_kernel<<<dim3(1024), blk, 0, stream>>>(
        STc, STbp, cnt, lists, Qb, batch, Bsum, b_bias, attnb);

    mfma_gemm_final<<<dim3(8, 128), blk, 0, stream>>>(attnb, Woutt, out);
}